// Round 7
// baseline (133.623 us; speedup 1.0000x reference)
//
#include <hip/hip_runtime.h>
#include <hip/hip_bf16.h>

// TritonDynamicAttention: blocksparse causal attention, B=2,H=16,S=2048,D=64, BLOCK=32.
// R5 (fixed): VALU diet (exp2 w/ log2e-folded Q, defer-max rescale skip, cvt_pkrtz
// packing, max3 trees), XCD-locality bid swizzle (4 bh per XCD -> K/V L2-resident),
// early-exit block-mask. R6 fix: PK union uses the builtin's own __fp16 vector type.

typedef _Float16 f16_t;
typedef f16_t  f16x8  __attribute__((ext_vector_type(8)));
typedef __fp16 fp16x2 __attribute__((ext_vector_type(2)));
typedef float  f32x4  __attribute__((ext_vector_type(4)));
typedef float  f32x16 __attribute__((ext_vector_type(16)));
typedef int    i32x4  __attribute__((ext_vector_type(4)));
typedef unsigned int u32x4 __attribute__((ext_vector_type(4)));

constexpr int Bc = 2, Hc = 16, Sc = 2048, Dc = 64;
constexpr int NB = Sc / 32;                              // 64 mask blocks per side
constexpr size_t QKV_ELEMS = (size_t)Bc * Hc * Sc * Dc;  // 4194304
constexpr float LOG2E = 1.4426950408889634f;

__device__ inline f32x16 mfma32(f16x8 a, f16x8 b, f32x16 c) {
    return __builtin_amdgcn_mfma_f32_32x32x16_f16(a, b, c, 0, 0, 0);
}
__device__ inline float fexp2(float x) { return __builtin_amdgcn_exp2f(x); }

union UB { u32x4 u; f16x8 v; };
union PK { fp16x2 h; unsigned int u; };

// ---------- fused prep: [0,2048) K->f16 | [2048,3072) V^T f16 | [3072,4096) blockmask --
__global__ __launch_bounds__(256) void k_prep(const float* __restrict__ K,
                                              const float* __restrict__ V,
                                              const int* __restrict__ mask,
                                              const float* __restrict__ bias,
                                              f16_t* __restrict__ kh,
                                              f16_t* __restrict__ vt,
                                              unsigned char* __restrict__ bm) {
    const int bid = blockIdx.x;
    const int t   = threadIdx.x;
    if (bid < 2048) {
        size_t i = ((size_t)bid * 256 + t) * 8;
        f32x4 a = *(const f32x4*)(K + i);
        f32x4 b = *(const f32x4*)(K + i + 4);
        float xs[8] = {a[0], a[1], a[2], a[3], b[0], b[1], b[2], b[3]};
        f16x8 h;
#pragma unroll
        for (int j = 0; j < 8; j++) h[j] = (f16_t)xs[j];
        *(f16x8*)(kh + i) = h;
    } else if (bid < 3072) {
        __shared__ f16_t tile[64 * 66];
        const int b2 = bid - 2048;
        const int bh = b2 >> 5;
        const int st = b2 & 31;
        {
            int sr = t >> 2, dseg = (t & 3) * 16;
            const float* vr = V + ((size_t)bh * Sc + (size_t)st * 64 + sr) * Dc + dseg;
#pragma unroll
            for (int c = 0; c < 4; c++) {
                f32x4 a = *(const f32x4*)(vr + c * 4);
#pragma unroll
                for (int j = 0; j < 4; j++) tile[sr * 66 + dseg + c * 4 + j] = (f16_t)a[j];
            }
        }
        __syncthreads();
        {
            int dr = t >> 2, sseg = (t & 3) * 16;
            f16x8 h0, h1;
#pragma unroll
            for (int j = 0; j < 8; j++) h0[j] = tile[(sseg + j) * 66 + dr];
#pragma unroll
            for (int j = 0; j < 8; j++) h1[j] = tile[(sseg + 8 + j) * 66 + dr];
            f16_t* outp = vt + ((size_t)bh * Dc + dr) * Sc + (size_t)st * 64 + sseg;
            *(f16x8*)outp = h0;
            *(f16x8*)(outp + 8) = h1;
        }
    } else {
        // ---- block mask with early-exit (mask values are nonnegative -> partial
        // sums are monotone lower bounds; certify 'active' after 4/32 rows) ----
        const int b3 = bid - 3072;
        const int h  = b3 >> 6;
        const int br = b3 & 63;
        float bv = bias[h];
        unsigned char* outp = bm + ((size_t)h * NB + br) * NB;
        if (bv > 0.f) {
            if (t < NB) outp[t] = 1;
            return;
        }
        int bc0 = t >> 3;
        int bc1 = 32 + bc0;
        const int* base = mask + ((size_t)h * Sc + (size_t)br * 32) * (size_t)Sc;
        const int* p0 = base + 4 * t;
        const int* p1 = base + 1024 + 4 * t;
        bool d0 = (bc0 <= br), d1 = (bc1 <= br);
        int acc0 = 0, acc1 = 0;
        if (d0) {
#pragma unroll
            for (int r = 0; r < 4; r++) {
                i32x4 vv = *(const i32x4*)(p0 + (size_t)r * Sc);
                acc0 += vv[0] + vv[1] + vv[2] + vv[3];
            }
        }
        if (d1) {
#pragma unroll
            for (int r = 0; r < 4; r++) {
                i32x4 vv = *(const i32x4*)(p1 + (size_t)r * Sc);
                acc1 += vv[0] + vv[1] + vv[2] + vv[3];
            }
        }
        int g0 = acc0, g1 = acc1;
#pragma unroll
        for (int off = 1; off < 8; off <<= 1) {
            g0 += __shfl_xor(g0, off);
            g1 += __shfl_xor(g1, off);
        }
        bool act0 = (float)g0 + bv > 0.f;   // certified active (partial >= 0 rest)
        bool act1 = (float)g1 + bv > 0.f;
        if (d0 && !act0) {
            for (int r = 4; r < 32; r++) {
                i32x4 vv = *(const i32x4*)(p0 + (size_t)r * Sc);
                acc0 += vv[0] + vv[1] + vv[2] + vv[3];
            }
            int s = acc0;
#pragma unroll
            for (int off = 1; off < 8; off <<= 1) s += __shfl_xor(s, off);
            act0 = (float)s + bv > 0.f;
        }
        if (d1 && !act1) {
            for (int r = 4; r < 32; r++) {
                i32x4 vv = *(const i32x4*)(p1 + (size_t)r * Sc);
                acc1 += vv[0] + vv[1] + vv[2] + vv[3];
            }
            int s = acc1;
#pragma unroll
            for (int off = 1; off < 8; off <<= 1) s += __shfl_xor(s, off);
            act1 = (float)s + bv > 0.f;
        }
        if ((t & 7) == 0) {
            if (d0) outp[bc0] = act0 ? 1 : 0;
            if (d1) outp[bc1] = act1 ? 1 : 0;
        }
    }
}

// ---------- flash blocksparse causal attention, 32x32 swapped, fp16, parity split ------
// Scores computed in log2 domain (Q pre-scaled by log2e); defer-max skips O-rescale
// unless a column's tile-max exceeds running max + 11 (P bounded by 2^11, f16-safe).
#define KLOAD(KB_, kb_) do {                                                   \
    _Pragma("unroll")                                                          \
    for (int kc_ = 0; kc_ < 4; kc_++)                                          \
        KB_[kc_] = *(const f16x8*)(khp + (size_t)(((kb_) * 32 + l31) * Dc)     \
                                   + kc_ * 16 + hi * 8);                       \
} while (0)

#define STEP(KB_, kb_) do {                                                    \
    if ((actmask >> (kb_)) & 1ull) {                                           \
        f16x8 va_[2][2];                                                       \
        _Pragma("unroll")                                                      \
        for (int t_ = 0; t_ < 2; t_++)                                         \
            _Pragma("unroll")                                                  \
            for (int c_ = 0; c_ < 2; c_++)                                     \
                va_[t_][c_] = *(const f16x8*)(vtp + (size_t)(t_ * 32 + l31) * Sc \
                                              + (kb_) * 32 + c_ * 16 + hi * 8);   \
        f32x16 st;                                                             \
        _Pragma("unroll")                                                      \
        for (int r_ = 0; r_ < 16; r_++) st[r_] = 0.f;                          \
        _Pragma("unroll")                                                      \
        for (int kc_ = 0; kc_ < 4; kc_++)                                      \
            st = mfma32(KB_[kc_], qh[kc_], st);                                \
        if ((kb_) == brow) {                                                   \
            _Pragma("unroll")                                                  \
            for (int r_ = 0; r_ < 16; r_++) {                                  \
                int kvl_ = (r_ & 3) + 8 * (r_ >> 2) + 4 * hi;                  \
                if (kvl_ > l31) st[r_] = -1e30f;                               \
            }                                                                  \
        }                                                                      \
        float a0_ = fmaxf(fmaxf(st[0], st[1]), st[2]);                         \
        float a1_ = fmaxf(fmaxf(st[3], st[4]), st[5]);                         \
        float a2_ = fmaxf(fmaxf(st[6], st[7]), st[8]);                         \
        float a3_ = fmaxf(fmaxf(st[9], st[10]), st[11]);                       \
        float a4_ = fmaxf(fmaxf(st[12], st[13]), st[14]);                      \
        float b0m_ = fmaxf(fmaxf(a0_, a1_), a2_);                              \
        float b1m_ = fmaxf(fmaxf(a3_, a4_), st[15]);                           \
        float mx_ = fmaxf(b0m_, b1m_);                                         \
        mx_ = fmaxf(mx_, __shfl_xor(mx_, 32));                                 \
        if (__ballot(mx_ > mrow + 11.0f)) {                                    \
            float mn_ = fmaxf(mrow, mx_);                                      \
            float al_ = fexp2(mrow - mn_);                                     \
            mrow = mn_;                                                        \
            lrow *= al_;                                                       \
            ot0 *= al_; ot1 *= al_;                                            \
        }                                                                      \
        _Pragma("unroll")                                                      \
        for (int r_ = 0; r_ < 16; r_++) st[r_] = fexp2(st[r_] - mrow);         \
        {                                                                      \
            float s0 = (st[0] + st[1]) + (st[2] + st[3]);                      \
            float s1 = (st[4] + st[5]) + (st[6] + st[7]);                      \
            float s2 = (st[8] + st[9]) + (st[10] + st[11]);                    \
            float s3 = (st[12] + st[13]) + (st[14] + st[15]);                  \
            lrow += ((s0 + s1) + (s2 + s3));                                   \
        }                                                                      \
        unsigned int pb_[8], qb_[8];                                           \
        _Pragma("unroll")                                                      \
        for (int i_ = 0; i_ < 8; i_++) {                                       \
            PK pk_;                                                            \
            pk_.h = __builtin_amdgcn_cvt_pkrtz(st[2 * i_], st[2 * i_ + 1]);    \
            pb_[i_] = pk_.u;                                                   \
        }                                                                      \
        _Pragma("unroll")                                                      \
        for (int i_ = 0; i_ < 8; i_++)                                         \
            qb_[i_] = (unsigned int)__shfl_xor((int)pb_[i_], 32);              \
        UB b0_, b1_;                                                           \
        b0_.u[0] = hi ? qb_[2] : pb_[0]; b0_.u[1] = hi ? qb_[3] : pb_[1];      \
        b0_.u[2] = hi ? pb_[2] : qb_[0]; b0_.u[3] = hi ? pb_[3] : qb_[1];      \
        b1_.u[0] = hi ? qb_[6] : pb_[4]; b1_.u[1] = hi ? qb_[7] : pb_[5];      \
        b1_.u[2] = hi ? pb_[6] : qb_[4]; b1_.u[3] = hi ? pb_[7] : qb_[5];      \
        ot0 = mfma32(va_[0][0], b0_.v, ot0);                                   \
        ot0 = mfma32(va_[0][1], b1_.v, ot0);                                   \
        ot1 = mfma32(va_[1][0], b0_.v, ot1);                                   \
        ot1 = mfma32(va_[1][1], b1_.v, ot1);                                   \
    }                                                                          \
} while (0)

__global__ __launch_bounds__(128, 4) void k_attn(const float* __restrict__ Q,
                                                 const f16_t* __restrict__ KH,
                                                 const f16_t* __restrict__ VT,
                                                 const unsigned char* __restrict__ BM,
                                                 float* __restrict__ Out) {
    __shared__ float lds_o[64 * 33];
    __shared__ float lds_m[32];
    __shared__ float lds_l[32];

    // XCD-locality swizzle: XCD = bid & 7 (dispatch round-robin); give each XCD
    // 4 bh (K/V working set 2MB < 4MB L2). Heavy block-rows first within slot.
    const int x  = blockIdx.x & 7;
    const int j  = blockIdx.x >> 3;        // 0..255
    const int bh = x * 4 + (j >> 6);
    const int qi = 63 - (j & 63);
    const int h  = bh & (Hc - 1);
    const int w    = threadIdx.x >> 6;
    const int lane = threadIdx.x & 63;
    const int l31  = lane & 31, hi = lane >> 5;

    const size_t bh_off = (size_t)bh * Sc * Dc;
    const float* q_ptr  = Q  + bh_off;
    const f16_t* khp    = KH + bh_off;
    const f16_t* vtp    = VT + bh_off;

    const int q0   = qi * 32;
    const int brow = qi;
    const unsigned char* bmrow = BM + ((size_t)h * NB + brow) * NB;
    const unsigned long long actmask = __ballot(bmrow[lane] != 0);

    // Q fragments (B-operand of S^T), pre-scaled by log2e for exp2 softmax
    f16x8 qh[4];
    {
        const float* qr = q_ptr + (size_t)(q0 + l31) * Dc + hi * 8;
#pragma unroll
        for (int kc = 0; kc < 4; kc++) {
            f32x4 a = *(const f32x4*)(qr + kc * 16);
            f32x4 b = *(const f32x4*)(qr + kc * 16 + 4);
            float xs[8] = {a[0], a[1], a[2], a[3], b[0], b[1], b[2], b[3]};
#pragma unroll
            for (int j2 = 0; j2 < 8; j2++) qh[kc][j2] = (f16_t)(xs[j2] * LOG2E);
        }
    }

    f32x16 ot0, ot1;
#pragma unroll
    for (int r = 0; r < 16; r++) { ot0[r] = 0.f; ot1[r] = 0.f; }
    float mrow = -INFINITY, lrow = 0.f;

    // this wave handles kb == w (mod 2), double-buffered
    f16x8 kbufA[4], kbufB[4];
    int ib = w;
    if (ib <= brow) KLOAD(kbufA, ib);
    while (ib <= brow) {
        if (ib + 2 <= brow) KLOAD(kbufB, ib + 2);
        STEP(kbufA, ib);
        ib += 2;
        if (ib > brow) break;
        if (ib + 2 <= brow) KLOAD(kbufA, ib + 2);
        STEP(kbufB, ib);
        ib += 2;
    }

    // ---- merge the two waves' partials (exact flash-decode merge, log2 domain) ----
    float lsum = lrow + __shfl_xor(lrow, 32);
    if (w == 1) {
#pragma unroll
        for (int r = 0; r < 16; r++) {
            int d0 = (r & 3) + 8 * (r >> 2) + 4 * hi;
            lds_o[d0 * 33 + l31]        = ot0[r];
            lds_o[(d0 + 32) * 33 + l31] = ot1[r];
        }
        if (hi == 0) { lds_m[l31] = mrow; lds_l[l31] = lsum; }
    }
    __syncthreads();
    if (w == 0) {
        float m1 = lds_m[l31], l1 = lds_l[l31];
        float mm = fmaxf(mrow, m1);
        float a0 = (mrow > -1e37f) ? fexp2(mrow - mm) : 0.f;
        float a1 = (m1   > -1e37f) ? fexp2(m1   - mm) : 0.f;
        float lt = lsum * a0 + l1 * a1;
        float inv = (lt > 0.f) ? (1.f / lt) : 0.f;
        float* op = Out + bh_off + (size_t)(q0 + l31) * Dc;
#pragma unroll
        for (int g = 0; g < 4; g++) {
            f32x4 w0, w1;
#pragma unroll
            for (int jj = 0; jj < 4; jj++) {
                int r = g * 4 + jj;
                int d0 = jj + 8 * g + 4 * hi;
                w0[jj] = (ot0[r] * a0 + lds_o[d0 * 33 + l31] * a1) * inv;
                w1[jj] = (ot1[r] * a0 + lds_o[(d0 + 32) * 33 + l31] * a1) * inv;
            }
            *(f32x4*)(op + g * 8 + hi * 4)      = w0;
            *(f32x4*)(op + 32 + g * 8 + hi * 4) = w1;
        }
    }
}

extern "C" void kernel_launch(void* const* d_in, const int* in_sizes, int n_in,
                              void* d_out, int out_size, void* d_ws, size_t ws_size,
                              hipStream_t stream) {
    const float* Q    = (const float*)d_in[0];
    const float* K    = (const float*)d_in[1];
    const float* V    = (const float*)d_in[2];
    const float* bias = (const float*)d_in[3];
    const int*   mask = (const int*)d_in[4];
    float* out = (float*)d_out;

    char* ws = (char*)d_ws;
    f16_t* kh = (f16_t*)ws;                                    // 8 MiB
    f16_t* vt = (f16_t*)(ws + QKV_ELEMS * 2);                  // 8 MiB
    unsigned char* bm = (unsigned char*)(ws + QKV_ELEMS * 4);  // 64 KiB

    k_prep <<<4096, 256, 0, stream>>>(K, V, mask, bias, kh, vt, bm);
    k_attn <<<Bc * Hc * NB, 128, 0, stream>>>(Q, kh, vt, bm, out);
}

// Round 8
// 110.281 us; speedup vs baseline: 1.2117x; 1.2117x over previous
//
#include <hip/hip_runtime.h>
#include <hip/hip_bf16.h>

// TritonDynamicAttention: blocksparse causal attention, B=2,H=16,S=2048,D=64, BLOCK=32.
// R8: revert XCD swizzle to R4 mapping (round-robin already gives per-XCD bh locality);
// replace all cross-half shfl_xor(32) with v_permlane32_swap (VALU pipe, not DS):
// one swap produces both exchange words -> 8 shfl + 8 sel become 4 permlane ops.
// Keeps: fp16 carrier, kv-parity 2-wave split + exact LDS merge, exp2 softmax w/
// log2e-folded Q, defer-max rescale skip, cvt_pkrtz packing, early-exit block mask.

typedef _Float16 f16_t;
typedef f16_t  f16x8  __attribute__((ext_vector_type(8)));
typedef __fp16 fp16x2 __attribute__((ext_vector_type(2)));
typedef float  f32x4  __attribute__((ext_vector_type(4)));
typedef float  f32x16 __attribute__((ext_vector_type(16)));
typedef int    i32x4  __attribute__((ext_vector_type(4)));
typedef int    i32x2  __attribute__((ext_vector_type(2)));
typedef unsigned int u32x4 __attribute__((ext_vector_type(4)));

constexpr int Bc = 2, Hc = 16, Sc = 2048, Dc = 64;
constexpr int NB = Sc / 32;                              // 64 mask blocks per side
constexpr size_t QKV_ELEMS = (size_t)Bc * Hc * Sc * Dc;  // 4194304
constexpr float LOG2E = 1.4426950408889634f;

__device__ inline f32x16 mfma32(f16x8 a, f16x8 b, f32x16 c) {
    return __builtin_amdgcn_mfma_f32_32x32x16_f16(a, b, c, 0, 0, 0);
}
__device__ inline float fexp2(float x) { return __builtin_amdgcn_exp2f(x); }

union UB { u32x4 u; f16x8 v; };
union PK { fp16x2 h; unsigned int u; };

#if __has_builtin(__builtin_amdgcn_permlane32_swap)
#define HAVE_PLSWAP 1
// out[0]: lanes<32 = a(own), lanes>=32 = a from partner (lane-32)  [b's low half]
// out[1]: lanes<32 = a from partner (lane+32) [a's high half], lanes>=32 = b(own)
__device__ inline i32x2 plswap(unsigned int a, unsigned int b) {
    return __builtin_amdgcn_permlane32_swap((int)a, (int)b, false, false);
}
__device__ inline float xhalf_max(float x) {
    i32x2 s = plswap((unsigned int)__float_as_int(x), (unsigned int)__float_as_int(x));
    return fmaxf(__int_as_float(s[0]), __int_as_float(s[1]));
}
__device__ inline float xhalf_sum(float x) {
    i32x2 s = plswap((unsigned int)__float_as_int(x), (unsigned int)__float_as_int(x));
    return __int_as_float(s[0]) + __int_as_float(s[1]);
}
#else
#define HAVE_PLSWAP 0
__device__ inline float xhalf_max(float x) { return fmaxf(x, __shfl_xor(x, 32)); }
__device__ inline float xhalf_sum(float x) { return x + __shfl_xor(x, 32); }
#endif

// ---------- fused prep: [0,2048) K->f16 | [2048,3072) V^T f16 | [3072,4096) blockmask --
__global__ __launch_bounds__(256) void k_prep(const float* __restrict__ K,
                                              const float* __restrict__ V,
                                              const int* __restrict__ mask,
                                              const float* __restrict__ bias,
                                              f16_t* __restrict__ kh,
                                              f16_t* __restrict__ vt,
                                              unsigned char* __restrict__ bm) {
    const int bid = blockIdx.x;
    const int t   = threadIdx.x;
    if (bid < 2048) {
        size_t i = ((size_t)bid * 256 + t) * 8;
        f32x4 a = *(const f32x4*)(K + i);
        f32x4 b = *(const f32x4*)(K + i + 4);
        float xs[8] = {a[0], a[1], a[2], a[3], b[0], b[1], b[2], b[3]};
        f16x8 h;
#pragma unroll
        for (int j = 0; j < 8; j++) h[j] = (f16_t)xs[j];
        *(f16x8*)(kh + i) = h;
    } else if (bid < 3072) {
        __shared__ f16_t tile[64 * 66];
        const int b2 = bid - 2048;
        const int bh = b2 >> 5;
        const int st = b2 & 31;
        {
            int sr = t >> 2, dseg = (t & 3) * 16;
            const float* vr = V + ((size_t)bh * Sc + (size_t)st * 64 + sr) * Dc + dseg;
#pragma unroll
            for (int c = 0; c < 4; c++) {
                f32x4 a = *(const f32x4*)(vr + c * 4);
#pragma unroll
                for (int j = 0; j < 4; j++) tile[sr * 66 + dseg + c * 4 + j] = (f16_t)a[j];
            }
        }
        __syncthreads();
        {
            int dr = t >> 2, sseg = (t & 3) * 16;
            f16x8 h0, h1;
#pragma unroll
            for (int j = 0; j < 8; j++) h0[j] = tile[(sseg + j) * 66 + dr];
#pragma unroll
            for (int j = 0; j < 8; j++) h1[j] = tile[(sseg + 8 + j) * 66 + dr];
            f16_t* outp = vt + ((size_t)bh * Dc + dr) * Sc + (size_t)st * 64 + sseg;
            *(f16x8*)outp = h0;
            *(f16x8*)(outp + 8) = h1;
        }
    } else {
        // ---- block mask with early-exit (mask values nonnegative -> partial sums are
        // monotone lower bounds; certify 'active' after 4/32 rows) ----
        const int b3 = bid - 3072;
        const int h  = b3 >> 6;
        const int br = b3 & 63;
        float bv = bias[h];
        unsigned char* outp = bm + ((size_t)h * NB + br) * NB;
        if (bv > 0.f) {
            if (t < NB) outp[t] = 1;
            return;
        }
        int bc0 = t >> 3;
        int bc1 = 32 + bc0;
        const int* base = mask + ((size_t)h * Sc + (size_t)br * 32) * (size_t)Sc;
        const int* p0 = base + 4 * t;
        const int* p1 = base + 1024 + 4 * t;
        bool d0 = (bc0 <= br), d1 = (bc1 <= br);
        int acc0 = 0, acc1 = 0;
        if (d0) {
#pragma unroll
            for (int r = 0; r < 4; r++) {
                i32x4 vv = *(const i32x4*)(p0 + (size_t)r * Sc);
                acc0 += vv[0] + vv[1] + vv[2] + vv[3];
            }
        }
        if (d1) {
#pragma unroll
            for (int r = 0; r < 4; r++) {
                i32x4 vv = *(const i32x4*)(p1 + (size_t)r * Sc);
                acc1 += vv[0] + vv[1] + vv[2] + vv[3];
            }
        }
        int g0 = acc0, g1 = acc1;
#pragma unroll
        for (int off = 1; off < 8; off <<= 1) {
            g0 += __shfl_xor(g0, off);
            g1 += __shfl_xor(g1, off);
        }
        bool act0 = (float)g0 + bv > 0.f;   // certified active (remaining rows >= 0)
        bool act1 = (float)g1 + bv > 0.f;
        if (d0 && !act0) {
            for (int r = 4; r < 32; r++) {
                i32x4 vv = *(const i32x4*)(p0 + (size_t)r * Sc);
                acc0 += vv[0] + vv[1] + vv[2] + vv[3];
            }
            int s = acc0;
#pragma unroll
            for (int off = 1; off < 8; off <<= 1) s += __shfl_xor(s, off);
            act0 = (float)s + bv > 0.f;
        }
        if (d1 && !act1) {
            for (int r = 4; r < 32; r++) {
                i32x4 vv = *(const i32x4*)(p1 + (size_t)r * Sc);
                acc1 += vv[0] + vv[1] + vv[2] + vv[3];
            }
            int s = acc1;
#pragma unroll
            for (int off = 1; off < 8; off <<= 1) s += __shfl_xor(s, off);
            act1 = (float)s + bv > 0.f;
        }
        if ((t & 7) == 0) {
            if (d0) outp[bc0] = act0 ? 1 : 0;
            if (d1) outp[bc1] = act1 ? 1 : 0;
        }
    }
}

// ---------- flash blocksparse causal attention, 32x32 swapped, fp16, parity split ------
#define KLOAD(KB_, kb_) do {                                                   \
    _Pragma("unroll")                                                          \
    for (int kc_ = 0; kc_ < 4; kc_++)                                          \
        KB_[kc_] = *(const f16x8*)(khp + (size_t)(((kb_) * 32 + l31) * Dc)     \
                                   + kc_ * 16 + hi * 8);                       \
} while (0)

#if HAVE_PLSWAP
#define EXCHANGE_P do {                                                        \
        i32x2 e0_ = plswap(pb_[0], pb_[2]);                                    \
        i32x2 e1_ = plswap(pb_[1], pb_[3]);                                    \
        i32x2 e2_ = plswap(pb_[4], pb_[6]);                                    \
        i32x2 e3_ = plswap(pb_[5], pb_[7]);                                    \
        b0_.u[0] = (unsigned int)e0_[0]; b0_.u[1] = (unsigned int)e1_[0];      \
        b0_.u[2] = (unsigned int)e0_[1]; b0_.u[3] = (unsigned int)e1_[1];      \
        b1_.u[0] = (unsigned int)e2_[0]; b1_.u[1] = (unsigned int)e3_[0];      \
        b1_.u[2] = (unsigned int)e2_[1]; b1_.u[3] = (unsigned int)e3_[1];      \
} while (0)
#else
#define EXCHANGE_P do {                                                        \
        unsigned int qb_[8];                                                   \
        _Pragma("unroll")                                                      \
        for (int i_ = 0; i_ < 8; i_++)                                         \
            qb_[i_] = (unsigned int)__shfl_xor((int)pb_[i_], 32);              \
        b0_.u[0] = hi ? qb_[2] : pb_[0]; b0_.u[1] = hi ? qb_[3] : pb_[1];      \
        b0_.u[2] = hi ? pb_[2] : qb_[0]; b0_.u[3] = hi ? pb_[3] : qb_[1];      \
        b1_.u[0] = hi ? qb_[6] : pb_[4]; b1_.u[1] = hi ? qb_[7] : pb_[5];      \
        b1_.u[2] = hi ? pb_[6] : qb_[4]; b1_.u[3] = hi ? pb_[7] : qb_[5];      \
} while (0)
#endif

#define STEP(KB_, kb_) do {                                                    \
    if ((actmask >> (kb_)) & 1ull) {                                           \
        f16x8 va_[2][2];                                                       \
        _Pragma("unroll")                                                      \
        for (int t_ = 0; t_ < 2; t_++)                                         \
            _Pragma("unroll")                                                  \
            for (int c_ = 0; c_ < 2; c_++)                                     \
                va_[t_][c_] = *(const f16x8*)(vtp + (size_t)(t_ * 32 + l31) * Sc \
                                              + (kb_) * 32 + c_ * 16 + hi * 8);   \
        f32x16 st;                                                             \
        _Pragma("unroll")                                                      \
        for (int r_ = 0; r_ < 16; r_++) st[r_] = 0.f;                          \
        _Pragma("unroll")                                                      \
        for (int kc_ = 0; kc_ < 4; kc_++)                                      \
            st = mfma32(KB_[kc_], qh[kc_], st);                                \
        if ((kb_) == brow) {                                                   \
            _Pragma("unroll")                                                  \
            for (int r_ = 0; r_ < 16; r_++) {                                  \
                int kvl_ = (r_ & 3) + 8 * (r_ >> 2) + 4 * hi;                  \
                if (kvl_ > l31) st[r_] = -1e30f;                               \
            }                                                                  \
        }                                                                      \
        float a0_ = fmaxf(fmaxf(st[0], st[1]), st[2]);                         \
        float a1_ = fmaxf(fmaxf(st[3], st[4]), st[5]);                         \
        float a2_ = fmaxf(fmaxf(st[6], st[7]), st[8]);                         \
        float a3_ = fmaxf(fmaxf(st[9], st[10]), st[11]);                       \
        float a4_ = fmaxf(fmaxf(st[12], st[13]), st[14]);                      \
        float b0m_ = fmaxf(fmaxf(a0_, a1_), a2_);                              \
        float b1m_ = fmaxf(fmaxf(a3_, a4_), st[15]);                           \
        float mx_ = xhalf_max(fmaxf(b0m_, b1m_));                              \
        if (__ballot(mx_ > mrow + 11.0f)) {                                    \
            float mn_ = fmaxf(mrow, mx_);                                      \
            float al_ = fexp2(mrow - mn_);                                     \
            mrow = mn_;                                                        \
            lrow *= al_;                                                       \
            ot0 *= al_; ot1 *= al_;                                            \
        }                                                                      \
        _Pragma("unroll")                                                      \
        for (int r_ = 0; r_ < 16; r_++) st[r_] = fexp2(st[r_] - mrow);         \
        {                                                                      \
            float s0 = (st[0] + st[1]) + (st[2] + st[3]);                      \
            float s1 = (st[4] + st[5]) + (st[6] + st[7]);                      \
            float s2 = (st[8] + st[9]) + (st[10] + st[11]);                    \
            float s3 = (st[12] + st[13]) + (st[14] + st[15]);                  \
            lrow += ((s0 + s1) + (s2 + s3));                                   \
        }                                                                      \
        unsigned int pb_[8];                                                   \
        _Pragma("unroll")                                                      \
        for (int i_ = 0; i_ < 8; i_++) {                                       \
            PK pk_;                                                            \
            pk_.h = __builtin_amdgcn_cvt_pkrtz(st[2 * i_], st[2 * i_ + 1]);    \
            pb_[i_] = pk_.u;                                                   \
        }                                                                      \
        UB b0_, b1_;                                                           \
        EXCHANGE_P;                                                            \
        ot0 = mfma32(va_[0][0], b0_.v, ot0);                                   \
        ot0 = mfma32(va_[0][1], b1_.v, ot0);                                   \
        ot1 = mfma32(va_[1][0], b0_.v, ot1);                                   \
        ot1 = mfma32(va_[1][1], b1_.v, ot1);                                   \
    }                                                                          \
} while (0)

__global__ __launch_bounds__(128, 4) void k_attn(const float* __restrict__ Q,
                                                 const f16_t* __restrict__ KH,
                                                 const f16_t* __restrict__ VT,
                                                 const unsigned char* __restrict__ BM,
                                                 float* __restrict__ Out) {
    __shared__ float lds_o[64 * 33];
    __shared__ float lds_m[32];
    __shared__ float lds_l[32];

    // R4 mapping: heavy block-rows dispatch first; round-robin XCD dispatch already
    // pins each XCD to 4 fixed bh values (bid === x mod 8 -> bh in {x,x+8,x+16,x+24}).
    const int qi   = 63 - (int)(blockIdx.x >> 5);
    const int bh   = blockIdx.x & 31;
    const int h    = bh & (Hc - 1);
    const int w    = threadIdx.x >> 6;
    const int lane = threadIdx.x & 63;
    const int l31  = lane & 31, hi = lane >> 5;

    const size_t bh_off = (size_t)bh * Sc * Dc;
    const float* q_ptr  = Q  + bh_off;
    const f16_t* khp    = KH + bh_off;
    const f16_t* vtp    = VT + bh_off;

    const int q0   = qi * 32;
    const int brow = qi;
    const unsigned char* bmrow = BM + ((size_t)h * NB + brow) * NB;
    const unsigned long long actmask = __ballot(bmrow[lane] != 0);

    // Q fragments (B-operand of S^T), pre-scaled by log2e for exp2 softmax
    f16x8 qh[4];
    {
        const float* qr = q_ptr + (size_t)(q0 + l31) * Dc + hi * 8;
#pragma unroll
        for (int kc = 0; kc < 4; kc++) {
            f32x4 a = *(const f32x4*)(qr + kc * 16);
            f32x4 b = *(const f32x4*)(qr + kc * 16 + 4);
            float xs[8] = {a[0], a[1], a[2], a[3], b[0], b[1], b[2], b[3]};
#pragma unroll
            for (int j2 = 0; j2 < 8; j2++) qh[kc][j2] = (f16_t)(xs[j2] * LOG2E);
        }
    }

    f32x16 ot0, ot1;
#pragma unroll
    for (int r = 0; r < 16; r++) { ot0[r] = 0.f; ot1[r] = 0.f; }
    float mrow = -INFINITY, lrow = 0.f;

    // this wave handles kb == w (mod 2), double-buffered
    f16x8 kbufA[4], kbufB[4];
    int ib = w;
    if (ib <= brow) KLOAD(kbufA, ib);
    while (ib <= brow) {
        if (ib + 2 <= brow) KLOAD(kbufB, ib + 2);
        STEP(kbufA, ib);
        ib += 2;
        if (ib > brow) break;
        if (ib + 2 <= brow) KLOAD(kbufA, ib + 2);
        STEP(kbufB, ib);
        ib += 2;
    }

    // ---- merge the two waves' partials (exact flash-decode merge, log2 domain) ----
    float lsum = xhalf_sum(lrow);
    if (w == 1) {
#pragma unroll
        for (int r = 0; r < 16; r++) {
            int d0 = (r & 3) + 8 * (r >> 2) + 4 * hi;
            lds_o[d0 * 33 + l31]        = ot0[r];
            lds_o[(d0 + 32) * 33 + l31] = ot1[r];
        }
        if (hi == 0) { lds_m[l31] = mrow; lds_l[l31] = lsum; }
    }
    __syncthreads();
    if (w == 0) {
        float m1 = lds_m[l31], l1 = lds_l[l31];
        float mm = fmaxf(mrow, m1);
        float a0 = (mrow > -1e37f) ? fexp2(mrow - mm) : 0.f;
        float a1 = (m1   > -1e37f) ? fexp2(m1   - mm) : 0.f;
        float lt = lsum * a0 + l1 * a1;
        float inv = (lt > 0.f) ? (1.f / lt) : 0.f;
        float* op = Out + bh_off + (size_t)(q0 + l31) * Dc;
#pragma unroll
        for (int g = 0; g < 4; g++) {
            f32x4 w0, w1;
#pragma unroll
            for (int jj = 0; jj < 4; jj++) {
                int r = g * 4 + jj;
                int d0 = jj + 8 * g + 4 * hi;
                w0[jj] = (ot0[r] * a0 + lds_o[d0 * 33 + l31] * a1) * inv;
                w1[jj] = (ot1[r] * a0 + lds_o[(d0 + 32) * 33 + l31] * a1) * inv;
            }
            *(f32x4*)(op + g * 8 + hi * 4)      = w0;
            *(f32x4*)(op + 32 + g * 8 + hi * 4) = w1;
        }
    }
}

extern "C" void kernel_launch(void* const* d_in, const int* in_sizes, int n_in,
                              void* d_out, int out_size, void* d_ws, size_t ws_size,
                              hipStream_t stream) {
    const float* Q    = (const float*)d_in[0];
    const float* K    = (const float*)d_in[1];
    const float* V    = (const float*)d_in[2];
    const float* bias = (const float*)d_in[3];
    const int*   mask = (const int*)d_in[4];
    float* out = (float*)d_out;

    char* ws = (char*)d_ws;
    f16_t* kh = (f16_t*)ws;                                    // 8 MiB
    f16_t* vt = (f16_t*)(ws + QKV_ELEMS * 2);                  // 8 MiB
    unsigned char* bm = (unsigned char*)(ws + QKV_ELEMS * 4);  // 64 KiB

    k_prep <<<4096, 256, 0, stream>>>(K, V, mask, bias, kh, vt, bm);
    k_attn <<<Bc * Hc * NB, 128, 0, stream>>>(Q, kh, vt, bm, out);
}